// Round 4
// baseline (1113.917 us; speedup 1.0000x reference)
//
#include <hip/hip_runtime.h>
#include <hip/hip_bf16.h>
#include <cstdint>
#include <cstddef>

// Problem constants (B=16, S=1024, D=1024)
#define S_LEN   1024
#define D_DIM   1024
#define QK_DIM  128
#define EXP_DIM 2048
#define H_HEADS 8
#define DH_Q    16
#define DH_V    128
#define M_ROWS  16384         // B*S
#define NEG_INF (-1e30f)

typedef __bf16 bf16;
typedef __bf16 b16x4 __attribute__((ext_vector_type(4)));
typedef __bf16 b16x8 __attribute__((ext_vector_type(8)));
typedef float  fx4   __attribute__((ext_vector_type(4)));

// ---------- async global->LDS (16B per lane) ----------
__device__ __forceinline__ void load_lds16(const bf16* g, bf16* l) {
    __builtin_amdgcn_global_load_lds(
        (const __attribute__((address_space(1))) void*)g,
        (__attribute__((address_space(3))) void*)l, 16, 0, 0);
}

// ---------- dtype probe: flag=1 if float tensors are f32, 0 if bf16 ----------
__global__ void probe_kernel(const unsigned short* __restrict__ xr, int* __restrict__ flag) {
    const int tid = threadIdx.x;   // 64 threads
    float m = 0.f;
    for (int i = tid; i < 512; i += 64) {
        union { unsigned int u; float f; } c;
        c.u = ((unsigned int)xr[i]) << 16;
        float v = fabsf(c.f);
        if (!(v == v)) v = 3e38f;
        m = fmaxf(m, v);
    }
#pragma unroll
    for (int off = 32; off >= 1; off >>= 1) m = fmaxf(m, __shfl_xor(m, off));
    if (tid == 0) *flag = (m > 1e4f) ? 1 : 0;
}

__global__ void zero_flag_kernel(int* flag) { *flag = 0; }

// ---------- convert (f32|bf16) -> bf16, 4 elements/thread ----------
__global__ __launch_bounds__(256) void convert_kernel(const void* __restrict__ src,
                                                      bf16* __restrict__ dst,
                                                      const int* __restrict__ flag, int n4) {
    const int i = blockIdx.x * 256 + threadIdx.x;
    if (i >= n4) return;
    if (*flag) {
        const fx4 v = ((const fx4*)src)[i];
        b16x4 o;
#pragma unroll
        for (int k = 0; k < 4; ++k) o[k] = (bf16)v[k];
        ((b16x4*)dst)[i] = o;
    } else {
        ((b16x4*)dst)[i] = ((const b16x4*)src)[i];
    }
}

// ---------- LayerNorm (dtype-adaptive x, w) ----------
__global__ __launch_bounds__(256) void ln_kernel(const void* __restrict__ xv,
                                                 const void* __restrict__ wv,
                                                 bf16* __restrict__ xn,
                                                 const int* __restrict__ flag) {
    const int row = blockIdx.x;
    const int tid = threadIdx.x;
    const int f32 = *flag;
    float v[4];
    if (f32) {
        const fx4 t = ((const fx4*)xv)[(size_t)row * 256 + tid];
#pragma unroll
        for (int i = 0; i < 4; ++i) v[i] = t[i];
    } else {
        const b16x4 t = ((const b16x4*)xv)[(size_t)row * 256 + tid];
#pragma unroll
        for (int i = 0; i < 4; ++i) v[i] = (float)t[i];
    }
    float s = 0.f, ss = 0.f;
#pragma unroll
    for (int i = 0; i < 4; ++i) { s += v[i]; ss += v[i] * v[i]; }
#pragma unroll
    for (int off = 32; off >= 1; off >>= 1) {
        s  += __shfl_xor(s,  off);
        ss += __shfl_xor(ss, off);
    }
    __shared__ float ls[4], lss[4];
    const int wave = tid >> 6;
    if ((tid & 63) == 0) { ls[wave] = s; lss[wave] = ss; }
    __syncthreads();
    s  = ls[0]  + ls[1]  + ls[2]  + ls[3];
    ss = lss[0] + lss[1] + lss[2] + lss[3];
    const float mu  = s * (1.f / D_DIM);
    const float var = ss * (1.f / D_DIM) - mu * mu;
    const float r   = rsqrtf(var + 1e-5f);
    float w[4];
    if (f32) {
        const fx4 t = ((const fx4*)wv)[tid];
#pragma unroll
        for (int i = 0; i < 4; ++i) w[i] = t[i];
    } else {
        const b16x4 t = ((const b16x4*)wv)[tid];
#pragma unroll
        for (int i = 0; i < 4; ++i) w[i] = (float)t[i];
    }
    b16x4 o4;
#pragma unroll
    for (int i = 0; i < 4; ++i) o4[i] = (bf16)((v[i] - mu) * r * w[i]);
    ((b16x4*)(xn + (size_t)row * D_DIM))[tid] = o4;
}

__device__ __forceinline__ float gelu_exact(float x) {
    return 0.5f * x * (1.f + erff(x * 0.70710678118654752f));
}

// ---------- GEMM: acc[M,N] = A[M,K] * W[N,K]^T  (m97-style, 128x128 tile, BK=32) ----------
// EPI==0: C = bf16(acc)
// EPI==1: OutF[gr*N+gc] = float(acc + R)   (final output, f32; R dtype-adaptive)
// EPI==2: fused geglu: l = C[gr*2048+gc]; g = l*gelu(acc);
//         gc<1024 -> C[gr*2048+gc]=g ; else VH[gr*1024+gc-1024]=g
template <int EPI>
__global__ __launch_bounds__(256) void gemm_bt(const bf16* __restrict__ A,
                                               const bf16* __restrict__ W,
                                               const void* __restrict__ Rv,
                                               bf16* __restrict__ C,
                                               bf16* __restrict__ VH,
                                               float* __restrict__ OutF,
                                               const int* __restrict__ flag,
                                               int M, int N, int K) {
    __shared__ bf16 As[128 * 32];
    __shared__ bf16 Ws[128 * 32];
    const int tid  = threadIdx.x;
    const int wave = tid >> 6, lane = tid & 63;
    const int tile_n = blockIdx.x * 128;
    const int tile_m = blockIdx.y * 128;
    const int m_off = (wave >> 1) * 64, n_off = (wave & 1) * 64;

    fx4 acc[4][4] = {};

    const int c0 = wave * 128 + lane;
    const int c1 = c0 + 64;
    const int r0 = c0 >> 2, cc0 = (c0 & 3) * 8;
    const int r1 = c1 >> 2, cc1 = (c1 & 3) * 8;

    const int mrow = lane & 15, quad = lane >> 4;

    for (int k0 = 0; k0 < K; k0 += 32) {
        load_lds16(A + (size_t)(tile_m + r0) * K + k0 + cc0, &As[c0 * 8]);
        load_lds16(A + (size_t)(tile_m + r1) * K + k0 + cc1, &As[c1 * 8]);
        load_lds16(W + (size_t)(tile_n + r0) * K + k0 + cc0, &Ws[c0 * 8]);
        load_lds16(W + (size_t)(tile_n + r1) * K + k0 + cc1, &Ws[c1 * 8]);
        __syncthreads();

        b16x8 af[4], bfr[4];
#pragma unroll
        for (int i = 0; i < 4; ++i) {
            af[i]  = *(const b16x8*)&As[(m_off + i * 16 + mrow) * 32 + quad * 8];
            bfr[i] = *(const b16x8*)&Ws[(n_off + i * 16 + mrow) * 32 + quad * 8];
        }
#pragma unroll
        for (int mi = 0; mi < 4; ++mi)
#pragma unroll
            for (int ni = 0; ni < 4; ++ni)
                acc[mi][ni] = __builtin_amdgcn_mfma_f32_16x16x32_bf16(
                    af[mi], bfr[ni], acc[mi][ni], 0, 0, 0);
        __syncthreads();
    }

    const int f32 = (EPI == 1) ? *flag : 0;
    const int lcol = lane & 15, lrow4 = (lane >> 4) * 4;
#pragma unroll
    for (int mi = 0; mi < 4; ++mi)
#pragma unroll
        for (int ni = 0; ni < 4; ++ni)
#pragma unroll
            for (int r = 0; r < 4; ++r) {
                const int gr = tile_m + m_off + mi * 16 + lrow4 + r;
                const int gc = tile_n + n_off + ni * 16 + lcol;
                const float a = acc[mi][ni][r];
                if (EPI == 0) {
                    C[(size_t)gr * N + gc] = (bf16)a;
                } else if (EPI == 1) {
                    const size_t idx = (size_t)gr * N + gc;
                    const float rv = f32 ? ((const float*)Rv)[idx]
                                         : (float)((const bf16*)Rv)[idx];
                    OutF[idx] = a + rv;          // f32 output
                } else {
                    const float l = (float)C[(size_t)gr * 2048 + gc];
                    const float g = l * gelu_exact(a);
                    if (gc < 1024) C[(size_t)gr * 2048 + gc] = (bf16)g;
                    else           VH[(size_t)gr * 1024 + (gc - 1024)] = (bf16)g;
                }
            }
}

// ---------- Attention (flash-style, VALU; NaN-proof softmax) ----------
__global__ __launch_bounds__(256) void attn_kernel(const bf16* __restrict__ qk,
                                                   const bf16* __restrict__ vh,
                                                   const void* __restrict__ pbmv,
                                                   const int* __restrict__ fip,
                                                   const int* __restrict__ lip,
                                                   bf16* __restrict__ concatb,
                                                   const int* __restrict__ flag) {
    const int bh = blockIdx.x;
    const int qt = blockIdx.y;
    const int b = bh >> 3, h = bh & 7;
    const int q0 = qt * 64;
    const int tid = threadIdx.x;
    const int a = tid & 15;
    const int g = tid >> 4;

    __shared__ float Vs[64][128];
    __shared__ float Ps[64][68];
    __shared__ float Ks[64][20];
    __shared__ float Mrow[64], Lrow[64], Arow[64];

    const float pm = (*flag) ? ((const float*)pbmv)[0] : (float)((const bf16*)pbmv)[0];
    const float sp = (pm > 20.f) ? pm : log1pf(expf(pm));
    int fi = fip[0], li = lip[0];
    if (fi >= S_LEN) fi = 0;
    if (li >= S_LEN) li = 0;

    float Q[4][16];
#pragma unroll
    for (int rr = 0; rr < 4; ++rr) {
        const bf16* qp = qk + ((size_t)(b * S_LEN + q0 + a + 16 * rr)) * 256 + h * DH_Q;
#pragma unroll
        for (int d = 0; d < 16; ++d) Q[rr][d] = (float)qp[d];
    }

    if (tid < 64) { Mrow[tid] = -3e38f; Lrow[tid] = 0.f; }
    float O[4][8];
#pragma unroll
    for (int rr = 0; rr < 4; ++rr)
#pragma unroll
        for (int dd = 0; dd < 8; ++dd) O[rr][dd] = 0.f;
    __syncthreads();

    const int qmax = q0 + 63;
    for (int k0 = 0; k0 < S_LEN; k0 += 64) {
        const bool any = (k0 <= qmax) || ((qmax >= fi) && (k0 + 63 >= li));
        if (!any) continue;

        {
            const int jr = tid >> 2, d0 = (tid & 3) * 4;
            const b16x4 kv4 = *(const b16x4*)(qk + ((size_t)(b * S_LEN + k0 + jr)) * 256
                                              + QK_DIM + h * DH_Q + d0);
            fx4 kf;
#pragma unroll
            for (int i = 0; i < 4; ++i) kf[i] = (float)kv4[i];
            *(fx4*)&Ks[jr][d0] = kf;
        }
#pragma unroll
        for (int i = 0; i < 4; ++i) {
            const int e = (i * 256 + tid) * 8;
            const int jr = e >> 7, d0 = e & 127;
            const b16x8 v8 = *(const b16x8*)(vh + ((size_t)(b * S_LEN + k0 + jr)) * D_DIM
                                             + h * DH_V + d0);
            fx4 f0, f1;
#pragma unroll
            for (int q = 0; q < 4; ++q) { f0[q] = (float)v8[q]; f1[q] = (float)v8[4 + q]; }
            *(fx4*)&Vs[jr][d0]     = f0;
            *(fx4*)&Vs[jr][d0 + 4] = f1;
        }
        __syncthreads();

#pragma unroll
        for (int jj = 0; jj < 4; ++jj) {
            const int j  = g * 4 + jj;
            const int jg = k0 + j;
            const fx4 k0v = *(const fx4*)&Ks[j][0];
            const fx4 k1v = *(const fx4*)&Ks[j][4];
            const fx4 k2v = *(const fx4*)&Ks[j][8];
            const fx4 k3v = *(const fx4*)&Ks[j][12];
#pragma unroll
            for (int rr = 0; rr < 4; ++rr) {
                const int rg = q0 + a + 16 * rr;
                float dot = 0.f;
#pragma unroll
                for (int d = 0; d < 4; ++d)
                    dot += Q[rr][d] * k0v[d] + Q[rr][4 + d] * k1v[d]
                         + Q[rr][8 + d] * k2v[d] + Q[rr][12 + d] * k3v[d];
                const bool act = (jg <= rg) || ((rg >= fi) && (jg >= li));
                Ps[a + 16 * rr][j] = act ? (dot * 0.25f + sp * (float)(jg - rg)) : NEG_INF;
            }
        }
        __syncthreads();

        if (tid < 64) {
            const int r = tid;
            float mc = -3e38f;
#pragma unroll 8
            for (int j = 0; j < 64; ++j) mc = fmaxf(mc, Ps[r][j]);
            const float m_old = Mrow[r];
            const float m_new = fmaxf(m_old, mc);
            float alpha;
            if (m_old <= -1e29f) alpha = 0.f;
            else                 alpha = expf(m_old - m_new);
            float lsum = 0.f;
#pragma unroll 8
            for (int j = 0; j < 64; ++j) {
                const float s = Ps[r][j];
                const float p = (s <= -1e29f) ? 0.f : expf(s - m_new);
                Ps[r][j] = p;
                lsum += p;
            }
            Mrow[r] = m_new;
            Lrow[r] = alpha * Lrow[r] + lsum;
            Arow[r] = alpha;
        }
        __syncthreads();

#pragma unroll
        for (int rr = 0; rr < 4; ++rr) {
            const float al = Arow[a + 16 * rr];
#pragma unroll
            for (int dd = 0; dd < 8; ++dd) O[rr][dd] *= al;
        }
        for (int j4 = 0; j4 < 64; j4 += 4) {
            fx4 p[4];
#pragma unroll
            for (int rr = 0; rr < 4; ++rr) p[rr] = *(const fx4*)&Ps[a + 16 * rr][j4];
#pragma unroll
            for (int jj = 0; jj < 4; ++jj) {
                const fx4 v0 = *(const fx4*)&Vs[j4 + jj][g * 8];
                const fx4 v1 = *(const fx4*)&Vs[j4 + jj][g * 8 + 4];
#pragma unroll
                for (int rr = 0; rr < 4; ++rr) {
                    const float pv = p[rr][jj];
#pragma unroll
                    for (int dd = 0; dd < 4; ++dd) {
                        O[rr][dd]     += pv * v0[dd];
                        O[rr][4 + dd] += pv * v1[dd];
                    }
                }
            }
        }
        __syncthreads();
    }

#pragma unroll
    for (int rr = 0; rr < 4; ++rr) {
        const int r = a + 16 * rr;
        const float L = Lrow[r];
        const float inv = (L > 0.f) ? 1.f / L : 0.f;
        b16x8 o8;
#pragma unroll
        for (int dd = 0; dd < 8; ++dd) o8[dd] = (bf16)(O[rr][dd] * inv);
        *(b16x8*)(concatb + ((size_t)(b * S_LEN + q0 + r)) * EXP_DIM
                  + EXP_DIM / 2 + h * DH_V + g * 8) = o8;
    }
}

// ---------- workspace layout ----------
static constexpr size_t WS0_OFF  = 0;                           // concat: 67,108,864
static constexpr size_t QK_OFF   = 67108864;                    // qkb:     8,388,608
static constexpr size_t VH_OFF   = QK_OFF + 8388608;            // vh:     33,554,432
static constexpr size_t FLAG_OFF = VH_OFF + 33554432;           // 109,051,904
static constexpr size_t EW_OFF   = FLAG_OFF + 64;
static constexpr size_t PW_OFF   = EW_OFF + 8912896;
static constexpr size_t WS_FULL  = PW_OFF + 4194304;            // 122,159,168
static constexpr size_t WS_MIN   = FLAG_OFF + 64;

extern "C" void kernel_launch(void* const* d_in, const int* in_sizes, int n_in,
                              void* d_out, int out_size, void* d_ws, size_t ws_size,
                              hipStream_t stream) {
    const void* x         = d_in[0];
    const void* norm_w    = d_in[1];
    const void* expand_w  = d_in[2];
    const void* project_w = d_in[3];
    const void* pbm       = d_in[4];
    const int*  fip       = (const int*)d_in[5];
    const int*  lip       = (const int*)d_in[6];
    float* out = (float*)d_out;          // reference output dtype: float32

    if (ws_size < WS_MIN) return;

    char* ws = (char*)d_ws;
    bf16* ws0  = (bf16*)(ws + WS0_OFF);
    bf16* qkb  = (bf16*)(ws + QK_OFF);
    bf16* vh   = (bf16*)(ws + VH_OFF);
    int*  flag = (int*)(ws + FLAG_OFF);
    bf16* xn   = (bf16*)d_out;           // first 32 MB of d_out as xn scratch (dead before final GEMM)

    const bool can_convert = (ws_size >= WS_FULL);
    const bf16* EW;
    const bf16* PW;

    if (can_convert) {
        probe_kernel<<<1, 64, 0, stream>>>((const unsigned short*)x, flag);
        bf16* ewb = (bf16*)(ws + EW_OFF);
        bf16* pwb = (bf16*)(ws + PW_OFF);
        convert_kernel<<<4352, 256, 0, stream>>>(expand_w, ewb, flag, 4456448 / 4);
        convert_kernel<<<2048, 256, 0, stream>>>(project_w, pwb, flag, 2097152 / 4);
        EW = ewb; PW = pwb;
    } else {
        zero_flag_kernel<<<1, 1, 0, stream>>>(flag);
        EW = (const bf16*)expand_w; PW = (const bf16*)project_w;
    }

    ln_kernel<<<M_ROWS, 256, 0, stream>>>(x, norm_w, xn, flag);
    // q,k: expand rows 0..255
    gemm_bt<0><<<dim3(2, M_ROWS / 128), 256, 0, stream>>>(
        xn, EW, nullptr, qkb, nullptr, nullptr, flag, M_ROWS, 256, D_DIM);
    // lin: expand rows 256..2303 -> ws0
    gemm_bt<0><<<dim3(16, M_ROWS / 128), 256, 0, stream>>>(
        xn, EW + (size_t)256 * D_DIM, nullptr, ws0, nullptr, nullptr, flag, M_ROWS, 2048, D_DIM);
    // pre: expand rows 2304..4351; fused geglu epilogue
    gemm_bt<2><<<dim3(16, M_ROWS / 128), 256, 0, stream>>>(
        xn, EW + (size_t)2304 * D_DIM, nullptr, ws0, vh, nullptr, flag, M_ROWS, 2048, D_DIM);
    attn_kernel<<<dim3(128, 16), 256, 0, stream>>>(qkb, vh, pbm, fip, lip, ws0, flag);
    // out(f32) = concat @ project_w^T + x
    gemm_bt<1><<<dim3(8, M_ROWS / 128), 256, 0, stream>>>(
        ws0, PW, x, nullptr, nullptr, out, flag, M_ROWS, D_DIM, EXP_DIM);
}

// Round 5
// 671.791 us; speedup vs baseline: 1.6581x; 1.6581x over previous
//
#include <hip/hip_runtime.h>
#include <hip/hip_bf16.h>
#include <cstdint>
#include <cstddef>

// Problem constants (B=16, S=1024, D=1024)
#define S_LEN   1024
#define D_DIM   1024
#define QK_DIM  128
#define EXP_DIM 2048
#define H_HEADS 8
#define DH_Q    16
#define DH_V    128
#define M_ROWS  16384         // B*S
#define NEG_INF (-1e30f)

typedef __bf16 bf16;
typedef __bf16 b16x4 __attribute__((ext_vector_type(4)));
typedef __bf16 b16x8 __attribute__((ext_vector_type(8)));
typedef float  fx4   __attribute__((ext_vector_type(4)));
typedef float  f32x16 __attribute__((ext_vector_type(16)));

// ---------- async global->LDS (16B per lane) ----------
__device__ __forceinline__ void load_lds16(const bf16* g, bf16* l) {
    __builtin_amdgcn_global_load_lds(
        (const __attribute__((address_space(1))) void*)g,
        (__attribute__((address_space(3))) void*)l, 16, 0, 0);
}

// ---------- dtype probe: flag=1 if float tensors are f32, 0 if bf16 ----------
__global__ void probe_kernel(const unsigned short* __restrict__ xr, int* __restrict__ flag) {
    const int tid = threadIdx.x;   // 64 threads
    float m = 0.f;
    for (int i = tid; i < 512; i += 64) {
        union { unsigned int u; float f; } c;
        c.u = ((unsigned int)xr[i]) << 16;
        float v = fabsf(c.f);
        if (!(v == v)) v = 3e38f;
        m = fmaxf(m, v);
    }
#pragma unroll
    for (int off = 32; off >= 1; off >>= 1) m = fmaxf(m, __shfl_xor(m, off));
    if (tid == 0) *flag = (m > 1e4f) ? 1 : 0;
}

__global__ void zero_flag_kernel(int* flag) { *flag = 0; }

// ---------- convert (f32|bf16) -> bf16, 4 elements/thread ----------
__global__ __launch_bounds__(256) void convert_kernel(const void* __restrict__ src,
                                                      bf16* __restrict__ dst,
                                                      const int* __restrict__ flag, int n4) {
    const int i = blockIdx.x * 256 + threadIdx.x;
    if (i >= n4) return;
    if (*flag) {
        const fx4 v = ((const fx4*)src)[i];
        b16x4 o;
#pragma unroll
        for (int k = 0; k < 4; ++k) o[k] = (bf16)v[k];
        ((b16x4*)dst)[i] = o;
    } else {
        ((b16x4*)dst)[i] = ((const b16x4*)src)[i];
    }
}

// ---------- LayerNorm (dtype-adaptive x, w) ----------
__global__ __launch_bounds__(256) void ln_kernel(const void* __restrict__ xv,
                                                 const void* __restrict__ wv,
                                                 bf16* __restrict__ xn,
                                                 const int* __restrict__ flag) {
    const int row = blockIdx.x;
    const int tid = threadIdx.x;
    const int f32 = *flag;
    float v[4];
    if (f32) {
        const fx4 t = ((const fx4*)xv)[(size_t)row * 256 + tid];
#pragma unroll
        for (int i = 0; i < 4; ++i) v[i] = t[i];
    } else {
        const b16x4 t = ((const b16x4*)xv)[(size_t)row * 256 + tid];
#pragma unroll
        for (int i = 0; i < 4; ++i) v[i] = (float)t[i];
    }
    float s = 0.f, ss = 0.f;
#pragma unroll
    for (int i = 0; i < 4; ++i) { s += v[i]; ss += v[i] * v[i]; }
#pragma unroll
    for (int off = 32; off >= 1; off >>= 1) {
        s  += __shfl_xor(s,  off);
        ss += __shfl_xor(ss, off);
    }
    __shared__ float ls[4], lss[4];
    const int wave = tid >> 6;
    if ((tid & 63) == 0) { ls[wave] = s; lss[wave] = ss; }
    __syncthreads();
    s  = ls[0]  + ls[1]  + ls[2]  + ls[3];
    ss = lss[0] + lss[1] + lss[2] + lss[3];
    const float mu  = s * (1.f / D_DIM);
    const float var = ss * (1.f / D_DIM) - mu * mu;
    const float r   = rsqrtf(var + 1e-5f);
    float w[4];
    if (f32) {
        const fx4 t = ((const fx4*)wv)[tid];
#pragma unroll
        for (int i = 0; i < 4; ++i) w[i] = t[i];
    } else {
        const b16x4 t = ((const b16x4*)wv)[tid];
#pragma unroll
        for (int i = 0; i < 4; ++i) w[i] = (float)t[i];
    }
    b16x4 o4;
#pragma unroll
    for (int i = 0; i < 4; ++i) o4[i] = (bf16)((v[i] - mu) * r * w[i]);
    ((b16x4*)(xn + (size_t)row * D_DIM))[tid] = o4;
}

__device__ __forceinline__ float gelu_exact(float x) {
    return 0.5f * x * (1.f + erff(x * 0.70710678118654752f));
}

// ---------- GEMM: acc[M,N] = A[M,K] * W[N,K]^T  (m97-style, 128x128 tile, BK=32) ----------
template <int EPI>
__global__ __launch_bounds__(256) void gemm_bt(const bf16* __restrict__ A,
                                               const bf16* __restrict__ W,
                                               const void* __restrict__ Rv,
                                               bf16* __restrict__ C,
                                               bf16* __restrict__ VH,
                                               float* __restrict__ OutF,
                                               const int* __restrict__ flag,
                                               int M, int N, int K) {
    __shared__ bf16 As[128 * 32];
    __shared__ bf16 Ws[128 * 32];
    const int tid  = threadIdx.x;
    const int wave = tid >> 6, lane = tid & 63;
    const int tile_n = blockIdx.x * 128;
    const int tile_m = blockIdx.y * 128;
    const int m_off = (wave >> 1) * 64, n_off = (wave & 1) * 64;

    fx4 acc[4][4] = {};

    const int c0 = wave * 128 + lane;
    const int c1 = c0 + 64;
    const int r0 = c0 >> 2, cc0 = (c0 & 3) * 8;
    const int r1 = c1 >> 2, cc1 = (c1 & 3) * 8;

    const int mrow = lane & 15, quad = lane >> 4;

    for (int k0 = 0; k0 < K; k0 += 32) {
        load_lds16(A + (size_t)(tile_m + r0) * K + k0 + cc0, &As[c0 * 8]);
        load_lds16(A + (size_t)(tile_m + r1) * K + k0 + cc1, &As[c1 * 8]);
        load_lds16(W + (size_t)(tile_n + r0) * K + k0 + cc0, &Ws[c0 * 8]);
        load_lds16(W + (size_t)(tile_n + r1) * K + k0 + cc1, &Ws[c1 * 8]);
        __syncthreads();

        b16x8 af[4], bfr[4];
#pragma unroll
        for (int i = 0; i < 4; ++i) {
            af[i]  = *(const b16x8*)&As[(m_off + i * 16 + mrow) * 32 + quad * 8];
            bfr[i] = *(const b16x8*)&Ws[(n_off + i * 16 + mrow) * 32 + quad * 8];
        }
#pragma unroll
        for (int mi = 0; mi < 4; ++mi)
#pragma unroll
            for (int ni = 0; ni < 4; ++ni)
                acc[mi][ni] = __builtin_amdgcn_mfma_f32_16x16x32_bf16(
                    af[mi], bfr[ni], acc[mi][ni], 0, 0, 0);
        __syncthreads();
    }

    const int f32 = (EPI == 1) ? *flag : 0;
    const int lcol = lane & 15, lrow4 = (lane >> 4) * 4;
#pragma unroll
    for (int mi = 0; mi < 4; ++mi)
#pragma unroll
        for (int ni = 0; ni < 4; ++ni)
#pragma unroll
            for (int r = 0; r < 4; ++r) {
                const int gr = tile_m + m_off + mi * 16 + lrow4 + r;
                const int gc = tile_n + n_off + ni * 16 + lcol;
                const float a = acc[mi][ni][r];
                if (EPI == 0) {
                    C[(size_t)gr * N + gc] = (bf16)a;
                } else if (EPI == 1) {
                    const size_t idx = (size_t)gr * N + gc;
                    const float rv = f32 ? ((const float*)Rv)[idx]
                                         : (float)((const bf16*)Rv)[idx];
                    OutF[idx] = a + rv;          // f32 output
                } else {
                    const float l = (float)C[(size_t)gr * 2048 + gc];
                    const float g = l * gelu_exact(a);
                    if (gc < 1024) C[(size_t)gr * 2048 + gc] = (bf16)g;
                    else           VH[(size_t)gr * 1024 + (gc - 1024)] = (bf16)g;
                }
            }
}

// ---------- MFMA flash attention ----------
// grid (B*H, S/64), block 256 (4 waves). Per block: 64 q-rows, 64-key chunks.
// QK^T: mfma_f32_32x32x16_bf16, K=16=dh_q. Wave w: q-half=w>>1, key/dim-sect=w&1.
// A/B frag layout: m(or n)=lane&31, k=(lane>>5)*8+j. C/D: col=lane&31,
// row=(reg&3)+8*(reg>>2)+4*(lane>>5)  [m74/m101-verified].
__global__ __launch_bounds__(256) void attn_kernel(const bf16* __restrict__ qk,
                                                   const bf16* __restrict__ vh,
                                                   const void* __restrict__ pbmv,
                                                   const int* __restrict__ fip,
                                                   const int* __restrict__ lip,
                                                   bf16* __restrict__ concatb,
                                                   const int* __restrict__ flag) {
    const int bh = blockIdx.x;
    const int qt = blockIdx.y;
    const int b = bh >> 3, h = bh & 7;
    const int q0 = qt * 64;
    const int tid  = threadIdx.x;
    const int wave = tid >> 6, lane = tid & 63;
    const int lm = lane & 31, lh = lane >> 5;
    const int qhalf = wave >> 1, sect = wave & 1;

    __shared__ float Ps[64][68];    // raw scores (C-layout write, row read)
    __shared__ bf16  Pb[64][72];    // probs bf16 (A-layout rows), stride 144B
    __shared__ bf16  Vt[128][72];   // V transposed [dim][key], stride 144B
    __shared__ float Mrow[64], Lrow[64], Arow[64];

    const float pm = (*flag) ? ((const float*)pbmv)[0] : (float)((const bf16*)pbmv)[0];
    const float sp = (pm > 20.f) ? pm : log1pf(expf(pm));
    int fi = fip[0], li = lip[0];
    if (fi >= S_LEN) fi = 0;
    if (li >= S_LEN) li = 0;

    // persistent Q A-frag (rows qhalf*32+lm, dh k=lh*8..+8)
    const b16x8 qfrag = *(const b16x8*)(qk
        + ((size_t)(b * S_LEN + q0 + qhalf * 32 + lm)) * 256 + h * DH_Q + lh * 8);

    f32x16 accO[2] = {};            // O tile: rows qhalf*32+, dims sect*64 + nb*32
    if (tid < 64) { Mrow[tid] = -3e38f; Lrow[tid] = 0.f; }

    // V-stage mapping: key=tid&63, dims (tid>>6)*32 + i*8
    const int vkey = tid & 63;
    const int vd   = (tid >> 6) * 32;

    // softmax mapping: row=wave*16+(lane>>2), keys (lane&3)*16..+16
    const int srow = wave * 16 + (lane >> 2);
    const int skq  = (lane & 3) * 16;

    const int qmax = q0 + 63;
    for (int k0 = 0; k0 < S_LEN; k0 += 64) {
        const bool any = (k0 <= qmax) || ((qmax >= fi) && (k0 + 63 >= li));
        if (!any) continue;

        __syncthreads();   // protect Vt/Ps/Pb from prev-iter readers (also M/L init)

        // stage V transposed: Vt[dim][key]
#pragma unroll
        for (int i = 0; i < 4; ++i) {
            const int d0 = vd + i * 8;
            const b16x8 v8 = *(const b16x8*)(vh
                + ((size_t)(b * S_LEN + k0 + vkey)) * D_DIM + h * DH_V + d0);
#pragma unroll
            for (int j = 0; j < 8; ++j) Vt[d0 + j][vkey] = v8[j];
        }

        // QK^T: keys sect*32+lm, dh k=lh*8..+8
        {
            const b16x8 kfrag = *(const b16x8*)(qk
                + ((size_t)(b * S_LEN + k0 + sect * 32 + lm)) * 256
                + QK_DIM + h * DH_Q + lh * 8);
            f32x16 z = {};
            const f32x16 S = __builtin_amdgcn_mfma_f32_32x32x16_bf16(qfrag, kfrag, z, 0, 0, 0);
#pragma unroll
            for (int r = 0; r < 16; ++r) {
                const int row = qhalf * 32 + (r & 3) + 8 * (r >> 2) + 4 * lh;
                Ps[row][sect * 32 + lm] = S[r];
            }
        }
        __syncthreads();   // Vt + Ps ready

        // softmax: 4 threads/row, 16 keys each
        {
            const int rg = q0 + srow;
            float s[16];
#pragma unroll
            for (int i = 0; i < 4; ++i) {
                const fx4 t = *(const fx4*)&Ps[srow][skq + i * 4];
#pragma unroll
                for (int j = 0; j < 4; ++j) {
                    const int jg = k0 + skq + i * 4 + j;
                    const bool act = (jg <= rg) || ((rg >= fi) && (jg >= li));
                    s[i * 4 + j] = act ? (t[j] * 0.25f + sp * (float)(jg - rg)) : -3e38f;
                }
            }
            float mloc = -3e38f;
#pragma unroll
            for (int i = 0; i < 16; ++i) mloc = fmaxf(mloc, s[i]);
            mloc = fmaxf(mloc, __shfl_xor(mloc, 1));
            mloc = fmaxf(mloc, __shfl_xor(mloc, 2));
            const float m_old = Mrow[srow];
            const float m_new = fmaxf(m_old, mloc);
            const float alpha = (m_old <= -1e29f) ? 0.f : expf(m_old - m_new);
            float lsum = 0.f;
            b16x8 p0, p1;
#pragma unroll
            for (int i = 0; i < 16; ++i) {
                const float p = (s[i] <= -1e29f) ? 0.f : expf(s[i] - m_new);
                lsum += p;
                if (i < 8) p0[i] = (bf16)p; else p1[i - 8] = (bf16)p;
            }
            lsum += __shfl_xor(lsum, 1);
            lsum += __shfl_xor(lsum, 2);
            *(b16x8*)&Pb[srow][skq]     = p0;
            *(b16x8*)&Pb[srow][skq + 8] = p1;
            if ((lane & 3) == 0) {
                Mrow[srow] = m_new;
                Lrow[srow] = alpha * Lrow[srow] + lsum;
                Arow[srow] = alpha;
            }
        }
        __syncthreads();   // Pb + M/L/A ready

        // rescale O by alpha, then O += P @ V
        {
#pragma unroll
            for (int r = 0; r < 16; ++r) {
                const float al = Arow[qhalf * 32 + (r & 3) + 8 * (r >> 2) + 4 * lh];
                accO[0][r] *= al;
                accO[1][r] *= al;
            }
            b16x8 Af[4];
#pragma unroll
            for (int ks = 0; ks < 4; ++ks)
                Af[ks] = *(const b16x8*)&Pb[qhalf * 32 + lm][ks * 16 + lh * 8];
#pragma unroll
            for (int nb = 0; nb < 2; ++nb)
#pragma unroll
                for (int ks = 0; ks < 4; ++ks) {
                    const b16x8 Bf = *(const b16x8*)&Vt[sect * 64 + nb * 32 + lm][ks * 16 + lh * 8];
                    accO[nb] = __builtin_amdgcn_mfma_f32_32x32x16_bf16(Af[ks], Bf, accO[nb], 0, 0, 0);
                }
        }
    }

    // epilogue: normalize rows, write to concat[:, 1024 + h*128 + dim]
#pragma unroll
    for (int r = 0; r < 16; ++r) {
        const int row = qhalf * 32 + (r & 3) + 8 * (r >> 2) + 4 * lh;
        const float L = Lrow[row];
        const float inv = (L > 0.f) ? 1.f / L : 0.f;
        const size_t base = ((size_t)(b * S_LEN + q0 + row)) * EXP_DIM
                          + EXP_DIM / 2 + h * DH_V + sect * 64 + lm;
#pragma unroll
        for (int nb = 0; nb < 2; ++nb)
            concatb[base + nb * 32] = (bf16)(accO[nb][r] * inv);
    }
}

// ---------- workspace layout ----------
static constexpr size_t WS0_OFF  = 0;                           // concat: 67,108,864
static constexpr size_t QK_OFF   = 67108864;                    // qkb:     8,388,608
static constexpr size_t VH_OFF   = QK_OFF + 8388608;            // vh:     33,554,432
static constexpr size_t FLAG_OFF = VH_OFF + 33554432;           // 109,051,904
static constexpr size_t EW_OFF   = FLAG_OFF + 64;
static constexpr size_t PW_OFF   = EW_OFF + 8912896;
static constexpr size_t WS_FULL  = PW_OFF + 4194304;            // 122,159,168
static constexpr size_t WS_MIN   = FLAG_OFF + 64;

extern "C" void kernel_launch(void* const* d_in, const int* in_sizes, int n_in,
                              void* d_out, int out_size, void* d_ws, size_t ws_size,
                              hipStream_t stream) {
    const void* x         = d_in[0];
    const void* norm_w    = d_in[1];
    const void* expand_w  = d_in[2];
    const void* project_w = d_in[3];
    const void* pbm       = d_in[4];
    const int*  fip       = (const int*)d_in[5];
    const int*  lip       = (const int*)d_in[6];
    float* out = (float*)d_out;          // reference output dtype: float32

    if (ws_size < WS_MIN) return;

    char* ws = (char*)d_ws;
    bf16* ws0  = (bf16*)(ws + WS0_OFF);
    bf16* qkb  = (bf16*)(ws + QK_OFF);
    bf16* vh   = (bf16*)(ws + VH_OFF);
    int*  flag = (int*)(ws + FLAG_OFF);
    bf16* xn   = (bf16*)d_out;           // first 32 MB of d_out as xn scratch

    const bool can_convert = (ws_size >= WS_FULL);
    const bf16* EW;
    const bf16* PW;

    if (can_convert) {
        probe_kernel<<<1, 64, 0, stream>>>((const unsigned short*)x, flag);
        bf16* ewb = (bf16*)(ws + EW_OFF);
        bf16* pwb = (bf16*)(ws + PW_OFF);
        convert_kernel<<<4352, 256, 0, stream>>>(expand_w, ewb, flag, 4456448 / 4);
        convert_kernel<<<2048, 256, 0, stream>>>(project_w, pwb, flag, 2097152 / 4);
        EW = ewb; PW = pwb;
    } else {
        zero_flag_kernel<<<1, 1, 0, stream>>>(flag);
        EW = (const bf16*)expand_w; PW = (const bf16*)project_w;
    }

    ln_kernel<<<M_ROWS, 256, 0, stream>>>(x, norm_w, xn, flag);
    gemm_bt<0><<<dim3(2, M_ROWS / 128), 256, 0, stream>>>(
        xn, EW, nullptr, qkb, nullptr, nullptr, flag, M_ROWS, 256, D_DIM);
    gemm_bt<0><<<dim3(16, M_ROWS / 128), 256, 0, stream>>>(
        xn, EW + (size_t)256 * D_DIM, nullptr, ws0, nullptr, nullptr, flag, M_ROWS, 2048, D_DIM);
    gemm_bt<2><<<dim3(16, M_ROWS / 128), 256, 0, stream>>>(
        xn, EW + (size_t)2304 * D_DIM, nullptr, ws0, vh, nullptr, flag, M_ROWS, 2048, D_DIM);
    attn_kernel<<<dim3(128, 16), 256, 0, stream>>>(qkb, vh, pbm, fip, lip, ws0, flag);
    gemm_bt<1><<<dim3(8, M_ROWS / 128), 256, 0, stream>>>(
        ws0, PW, x, nullptr, nullptr, out, flag, M_ROWS, D_DIM, EXP_DIM);
}